// Round 9
// baseline (196.480 us; speedup 1.0000x reference)
//
#include <hip/hip_runtime.h>
#include <math.h>
#include <stdint.h>

// x, x_r: (1, 3, 32, 512, 512) fp32. size=64 -> hc=wc=32, nh=nw=16.
// P[t,ph,pw] = mean over (c=3, 32x32) of |x - x_r|/2   (3072 elems/patch)
// out = log( mean_t( max(0, max_{ph,pw} P) ) )  -- scalar fp32.
//
// Round 9: global_load_lds DMA (direct-to-LDS, nt) -- the one read path not
//   yet tried. Theory: VGPR-bound loads cap at ~6 B/cyc/CU in the TCP->VGPR
//   return path (structure-invariant across rounds 7-8); DMA-to-LDS bypasses
//   it. Block = contiguous 1024-f4 chunk (16 KB/input, 32 KB LDS). Each wave
//   DMAs slots s = i*4+wave (i=0..3) for A and C; readback idx = i*256+tid
//   touches exactly those slots -> per-wave s_waitcnt, no barrier.
//   pw bin = (tid&127)>>3 constant per thread -> scalar accumulator.
// Kernel 2: one 1024-thread block: sum 12 chunk-contributions per patch
//   (3 ch x 4 row-quarters), per-t max, clamp, mean, log.

typedef float vf4 __attribute__((ext_vector_type(4)));
typedef __attribute__((address_space(1))) const void gas_void;
typedef __attribute__((address_space(3))) void lds_void;

__global__ __launch_bounds__(256) void patch_sum_kernel(
    const float* __restrict__ x, const float* __restrict__ xr,
    float* __restrict__ part) {
  __shared__ vf4 ldsA[1024];         // 16 KB
  __shared__ vf4 ldsC[1024];         // 16 KB
  const int b   = blockIdx.x;        // 0..6143, chunk = contiguous 1024 f4
  const int tid = threadIdx.x;
  const int wave = tid >> 6;
  const int lane = tid & 63;

  const vf4* a4 = (const vf4*)x  + (size_t)b * 1024;
  const vf4* c4 = (const vf4*)xr + (size_t)b * 1024;

#pragma unroll
  for (int i = 0; i < 4; ++i) {
    const int s = i * 4 + wave;      // slot 0..15 (64 f4 = 1 KiB per slot)
    __builtin_amdgcn_global_load_lds(
        (gas_void*)(uintptr_t)(a4 + (size_t)s * 64 + lane),
        (lds_void*)(uintptr_t)(ldsA + s * 64), 16, 0, 2 /*nt*/);
    __builtin_amdgcn_global_load_lds(
        (gas_void*)(uintptr_t)(c4 + (size_t)s * 64 + lane),
        (lds_void*)(uintptr_t)(ldsC + s * 64), 16, 0, 2 /*nt*/);
  }
  __builtin_amdgcn_s_waitcnt(0);     // per-wave drain; own slots only
  __builtin_amdgcn_sched_barrier(0); // keep ds_reads after the wait

  float s0 = 0.f, s1 = 0.f, s2 = 0.f, s3 = 0.f;
#pragma unroll
  for (int i = 0; i < 4; ++i) {
    vf4 a = ldsA[i * 256 + tid];     // slot = i*4 + wave : own wave's data
    vf4 c = ldsC[i * 256 + tid];
    s0 += fabsf(a.x - c.x);
    s1 += fabsf(a.y - c.y);
    s2 += fabsf(a.z - c.z);
    s3 += fabsf(a.w - c.w);
  }
  float acc = (s0 + s1) + (s2 + s3);

  // chunk = 8 rows x 128 f4 -> col4 = idx&127 = tid&127 -> bin = (tid&127)>>3
  acc += __shfl_down(acc, 4, 8);
  acc += __shfl_down(acc, 2, 8);
  acc += __shfl_down(acc, 1, 8);
  __shared__ float sb[32];
  if ((tid & 7) == 0) sb[tid >> 3] = acc;
  __syncthreads();
  if (tid < 16) part[(size_t)b * 16 + tid] = sb[tid] + sb[tid + 16];
}

__global__ __launch_bounds__(1024) void finalize_kernel(
    const float* __restrict__ part, float* __restrict__ out) {
  const int tid = threadIdx.x;
  const int t = tid >> 5;             // 0..31
  const int j = tid & 31;
  float m = -1e30f;
#pragma unroll
  for (int k = 0; k < 8; ++k) {
    int p = t * 256 + j + 32 * k;     // patch id within frame t
    int ph = (p >> 4) & 15;
    int pw = p & 15;
    float v = 0.f;
#pragma unroll
    for (int ch = 0; ch < 3; ++ch) {
#pragma unroll
      for (int q = 0; q < 4; ++q) {   // 4 row-quarters per (ch,t,ph)
        int idx = (ch * 2048 + t * 64 + ph * 4 + q) * 16 + pw;
        v += part[idx];
      }
    }
    m = fmaxf(m, v);
  }
#pragma unroll
  for (int o = 16; o > 0; o >>= 1) m = fmaxf(m, __shfl_down(m, o, 32));
  __shared__ float s[32];
  if (j == 0) s[t] = fmaxf(m * (0.5f / 3072.0f), 0.f);  // scale + clamp at 0
  __syncthreads();
  if (tid < 32) {
    float v = s[tid];
#pragma unroll
    for (int o = 16; o > 0; o >>= 1) v += __shfl_down(v, o, 32);
    if (tid == 0) out[0] = logf(v * (1.0f / 32.0f));
  }
}

extern "C" void kernel_launch(void* const* d_in, const int* in_sizes, int n_in,
                              void* d_out, int out_size, void* d_ws, size_t ws_size,
                              hipStream_t stream) {
  const float* x  = (const float*)d_in[0];
  const float* xr = (const float*)d_in[1];
  float* part = (float*)d_ws;        // 6144*16 floats = 384 KB scratch
  float* out  = (float*)d_out;

  patch_sum_kernel<<<6144, 256, 0, stream>>>(x, xr, part);
  finalize_kernel<<<1, 1024, 0, stream>>>(part, out);
}

// Round 10
// 194.535 us; speedup vs baseline: 1.0100x; 1.0100x over previous
//
#include <hip/hip_runtime.h>
#include <math.h>
#include <stdint.h>

// x, x_r: (1, 3, 32, 512, 512) fp32. size=64 -> hc=wc=32, nh=nw=16.
// P[t,ph,pw] = mean over (c=3, 32x32) of |x - x_r|/2   (3072 elems/patch)
// out = log( mean_t( max(0, max_{ph,pw} P) ) )  -- scalar fp32.
//
// Round 10: DUAL-PATH read — nt VGPR loads (low half of chunk) + DMA-to-LDS
//   (high half) in flight concurrently in the same wave. Decides whether the
//   ~3.7 TB/s cap (identical for both paths in rounds 8/9) is per-path
//   (-> aggregates to ~2x) or a shared TCP/fabric line-rate (-> neutral).
//   Block = contiguous 2048-f4 chunk (16 rows x 512 cols of a (ch,t) frame),
//   b = ch*1024 + t*32 + ph*2 + half. For any f4 idx in the chunk:
//   col4 = idx&127 -> pw bin = (tid&127)>>3 constant per thread for BOTH the
//   VGPR part (idx = i*256+tid) and the LDS readback (idx = 1024 + i*256+tid)
//   -> one scalar accumulator. DMA slot s = i*4+wave writes ldsX[s*64+lane];
//   readback i*256+tid touches exactly the issuing wave's slots.
// Kernel 2: one 1024-thread block: sum 6 chunk-contributions per patch,
//   per-t max, clamp, mean, log (round-7 version, measured fast).

typedef float vf4 __attribute__((ext_vector_type(4)));
typedef __attribute__((address_space(1))) const void gas_void;
typedef __attribute__((address_space(3))) void lds_void;

__global__ __launch_bounds__(256) void patch_sum_kernel(
    const float* __restrict__ x, const float* __restrict__ xr,
    float* __restrict__ part) {
  __shared__ vf4 ldsA[1024];         // 16 KB : high half of A chunk
  __shared__ vf4 ldsC[1024];         // 16 KB : high half of C chunk
  const int b    = blockIdx.x;       // 0..3071, chunk = contiguous 2048 f4
  const int tid  = threadIdx.x;
  const int wave = tid >> 6;
  const int lane = tid & 63;

  const vf4* a4 = (const vf4*)x  + (size_t)b * 2048;
  const vf4* c4 = (const vf4*)xr + (size_t)b * 2048;

  // Path 1 (issued first, stays in flight): DMA high 1024 f4 of each input.
#pragma unroll
  for (int i = 0; i < 4; ++i) {
    const int s = i * 4 + wave;      // slot 0..15, 64 f4 = 1 KiB per slot
    __builtin_amdgcn_global_load_lds(
        (gas_void*)(uintptr_t)(a4 + 1024 + (size_t)s * 64 + lane),
        (lds_void*)(uintptr_t)(ldsA + s * 64), 16, 0, 2 /*nt*/);
    __builtin_amdgcn_global_load_lds(
        (gas_void*)(uintptr_t)(c4 + 1024 + (size_t)s * 64 + lane),
        (lds_void*)(uintptr_t)(ldsC + s * 64), 16, 0, 2 /*nt*/);
  }

  // Path 2: nt VGPR loads of low 1024 f4 of each input.
  vf4 a[4], c[4];
#pragma unroll
  for (int i = 0; i < 4; ++i) a[i] = __builtin_nontemporal_load(&a4[i * 256 + tid]);
#pragma unroll
  for (int i = 0; i < 4; ++i) c[i] = __builtin_nontemporal_load(&c4[i * 256 + tid]);

  float s0 = 0.f, s1 = 0.f, s2 = 0.f, s3 = 0.f;
#pragma unroll
  for (int i = 0; i < 4; ++i) {
    s0 += fabsf(a[i].x - c[i].x);
    s1 += fabsf(a[i].y - c[i].y);
    s2 += fabsf(a[i].z - c[i].z);
    s3 += fabsf(a[i].w - c[i].w);
  }

  __builtin_amdgcn_s_waitcnt(0);     // drain DMAs (own wave's slots only)
  __builtin_amdgcn_sched_barrier(0); // keep ds_reads after the wait
#pragma unroll
  for (int i = 0; i < 4; ++i) {
    vf4 ah = ldsA[i * 256 + tid];
    vf4 ch = ldsC[i * 256 + tid];
    s0 += fabsf(ah.x - ch.x);
    s1 += fabsf(ah.y - ch.y);
    s2 += fabsf(ah.z - ch.z);
    s3 += fabsf(ah.w - ch.w);
  }
  float acc = (s0 + s1) + (s2 + s3);

  // 16 pw bins; thread bin = (tid&127)>>3. Reduce 8 consecutive lanes, then
  // 32 leaders land in LDS; combine pairs.
  acc += __shfl_down(acc, 4, 8);
  acc += __shfl_down(acc, 2, 8);
  acc += __shfl_down(acc, 1, 8);
  __shared__ float sb[32];
  if ((tid & 7) == 0) sb[tid >> 3] = acc;
  __syncthreads();
  if (tid < 16) part[(size_t)b * 16 + tid] = sb[tid] + sb[tid + 16];
}

__global__ __launch_bounds__(1024) void finalize_kernel(
    const float* __restrict__ part, float* __restrict__ out) {
  const int tid = threadIdx.x;
  const int t = tid >> 5;             // 0..31
  const int j = tid & 31;
  float m = -1e30f;
#pragma unroll
  for (int k = 0; k < 8; ++k) {
    int p = t * 256 + j + 32 * k;     // patch id within frame t
    int ph = (p >> 4) & 15;
    int pw = p & 15;
    float v = 0.f;
#pragma unroll
    for (int ch = 0; ch < 3; ++ch) {
#pragma unroll
      for (int half = 0; half < 2; ++half) {
        int idx = ((ch << 10) + (t << 5) + (ph << 1) + half) * 16 + pw;
        v += part[idx];
      }
    }
    m = fmaxf(m, v);
  }
#pragma unroll
  for (int o = 16; o > 0; o >>= 1) m = fmaxf(m, __shfl_down(m, o, 32));
  __shared__ float s[32];
  if (j == 0) s[t] = fmaxf(m * (0.5f / 3072.0f), 0.f);  // scale + clamp at 0
  __syncthreads();
  if (tid < 32) {
    float v = s[tid];
#pragma unroll
    for (int o = 16; o > 0; o >>= 1) v += __shfl_down(v, o, 32);
    if (tid == 0) out[0] = logf(v * (1.0f / 32.0f));
  }
}

extern "C" void kernel_launch(void* const* d_in, const int* in_sizes, int n_in,
                              void* d_out, int out_size, void* d_ws, size_t ws_size,
                              hipStream_t stream) {
  const float* x  = (const float*)d_in[0];
  const float* xr = (const float*)d_in[1];
  float* part = (float*)d_ws;        // 3072*16 floats = 192 KB scratch
  float* out  = (float*)d_out;

  patch_sum_kernel<<<3072, 256, 0, stream>>>(x, xr, part);
  finalize_kernel<<<1, 1024, 0, stream>>>(part, out);
}